// Round 16
// baseline (50.955 us; speedup 1.0000x reference)
//
#include <hip/hip_runtime.h>
#include <hip/hip_bf16.h>
#include <math.h>

#define TILE_X 16
#define TILE_Y 32
#define HALO_X 18
#define HALO_Y 34
#define NPIX   (HALO_X*HALO_Y)   // 612
#define NLVL   16
#define ARENA  1129              // max live pair: s(14)+s(15) = 464+665

typedef float v2f __attribute__((ext_vector_type(2)));

// Per-level corner arena offsets. Live set at iter l = {read l, write l+1 mod 16};
// ALL cyclic-adjacent pairs disjoint (incl. wrap (15,0): [0,665) vs [1050,1062));
// other overlaps barrier-separated in time.
// sizes: l0..l15 = 12,12,12,20,20,24,35,40,54,77,104,144,209,299,464,665
__device__ __constant__ const short LVL_OFF[16] =
    {1050,1038,1026,1006,986,962,927,887,833,756,652,508,299,0,665,0};

// ---------------- prep kernel: 4 blocks, one per batch ----------------
// ws layout (floats): [32..32+3456) Wp[b][l][tap][o][2]
__global__ __launch_bounds__(256) void prep_kernel(
    const float* __restrict__ s,        // (4,512)
    const float* __restrict__ weight,   // (3,32,3,3) = 864
    const float* __restrict__ affine_w, // (32,512)
    const float* __restrict__ affine_b, // (32,)
    float* __restrict__ ws)
{
    __shared__ float styles[32];
    __shared__ float dcoef[3];
    const int b   = blockIdx.x;
    const int tid = threadIdx.x;

    // styles[c] = dot(s[b,:], affine_w[c,:]) / sqrt(512) + affine_b[c]
    {
        int c = tid >> 3, g = tid & 7;
        const float4* sv = (const float4*)(s + b*512 + g*64);
        const float4* wv = (const float4*)(affine_w + c*512 + g*64);
        float acc = 0.f;
        #pragma unroll
        for (int k = 0; k < 16; ++k) {
            float4 a = sv[k], w = wv[k];
            acc += a.x*w.x + a.y*w.y + a.z*w.z + a.w*w.w;
        }
        acc += __shfl_xor(acc, 1);
        acc += __shfl_xor(acc, 2);
        acc += __shfl_xor(acc, 4);
        if (g == 0)
            styles[c] = acc * 0.044194173824159216f + affine_b[c];
    }
    __syncthreads();

    if (tid < 24) {
        int o = tid >> 3, g = tid & 7;
        float sum = 0.f;
        #pragma unroll
        for (int ci = 0; ci < 4; ++ci) {
            int c = 4*g + ci;
            float st = styles[c];
            #pragma unroll
            for (int k = 0; k < 9; ++k) {
                float w = weight[o*288 + c*9 + k] * st;
                sum = fmaf(w, w, sum);
            }
        }
        sum += __shfl_xor(sum, 1);
        sum += __shfl_xor(sum, 2);
        sum += __shfl_xor(sum, 4);
        if (g == 0)
            dcoef[o] = 1.0f / sqrtf(sum + 1e-8f);
    }
    __syncthreads();

    // Wp[b][l][tap][o][p] = weight[o, 2l+p, tap] * styles[2l+p] * dcoef[o]
    for (int t = tid; t < 864; t += 256) {
        int l   = t / 54;  int r2 = t % 54;
        int tap = r2 / 6;  int r3 = r2 % 6;
        int o   = r3 >> 1; int p  = r3 & 1;
        int c   = 2*l + p;
        ws[32 + b*864 + t] = weight[o*288 + c*9 + tap] * styles[c] * dcoef[o];
    }
}

// ---------------- main fused kernel ----------------
struct LP { int ixlo, iylo, nx, ncorn; unsigned magic; float r512; int off; };

__global__ __launch_bounds__(256, 8) void main_kernel(
    const float* __restrict__ tables,  // (4,16,65536,2)
    const float* __restrict__ ws,
    const float* __restrict__ bias,    // (3,)
    float* __restrict__ out)           // (4,3,512,512)
{
    __shared__ alignas(16) v2f feat2[2][NPIX];     // 9792 B
    __shared__ alignas(16) int lpbuf[NLVL][8];     // 512 B
    __shared__ v2f arena[ARENA];                   // 9032 B (per-level offsets)
    // total 19336 B -> 8 blocks/CU

    // XCD-aware bijective swizzle (2048 = 8 XCDs x 256)
    const int blk   = ((blockIdx.x & 7) << 8) | (blockIdx.x >> 3);
    const int b     = blk >> 9;
    const int trem  = blk & 511;
    const int tileY = trem >> 5;        // 0..15
    const int tileX = trem & 31;        // 0..31
    const int gx0 = tileX*TILE_X - 1, gy0 = tileY*TILE_Y - 1;
    const int tid = threadIdx.x;

    // Level-phase stagger: co-resident blocks start at different levels so
    // their LDS-heavy (bilinear) and VALU-heavy (conv) phases interleave
    // instead of convoying. Level sum is commutative; arena schedule is
    // cyclic-adjacent-disjoint, so the rotation preserves all hazards.
    const int phase = blk & 15;

    const v2f* tbl_base = (const v2f*)tables;

    // ---- per-block LP table: 16 lanes compute all levels once ----
    if (tid < NLVL) {
        // res(l) = 16 * 2^(l/3) (growth = exp(ln32/15) = 2^(1/3) exactly)
        float res  = 16.0f * exp2f((float)tid * (1.0f/3.0f));
        float r512 = res * (1.0f/512.0f);
        int vx_lo = max(gx0, 0), vx_hi = min(gx0 + HALO_X - 1, 511);
        int vy_lo = max(gy0, 0), vy_hi = min(gy0 + HALO_Y - 1, 511);
        int xlo = (int)floorf((vx_lo + 0.5f) * r512);
        int xhi = (int)floorf((vx_hi + 0.5f) * r512);
        int ylo = (int)floorf((vy_lo + 0.5f) * r512);
        int yhi = (int)floorf((vy_hi + 0.5f) * r512);
        int nx = xhi - xlo + 2, ny = yhi - ylo + 2;
        lpbuf[tid][0] = xlo;
        lpbuf[tid][1] = ylo;
        lpbuf[tid][2] = nx;
        lpbuf[tid][3] = nx * ny;
        lpbuf[tid][4] = (int)(65536u / (unsigned)nx + 1u);
        lpbuf[tid][5] = __float_as_int(r512);
        lpbuf[tid][6] = (int)LVL_OFF[tid];
    }
    __syncthreads();

    auto readLP = [&](int l) {
        LP lp;
        int4 a = *(const int4*)&lpbuf[l][0];
        int4 c = *(const int4*)&lpbuf[l][4];
        lp.ixlo = a.x; lp.iylo = a.y; lp.nx = a.z; lp.ncorn = a.w;
        lp.magic = (unsigned)c.x; lp.r512 = __int_as_float(c.y); lp.off = c.z;
        return lp;
    };

    auto issue_fetch = [&](int lvl, const LP& lp, v2f* regs) {
        const v2f* tbl = tbl_base + ((size_t)((b << 4) + lvl) << 16);
        #pragma unroll
        for (int r = 0; r < 3; ++r) {
            int c = tid + (r << 8);
            if (c < lp.ncorn) {
                unsigned row = ((unsigned)c * lp.magic) >> 16;
                unsigned col = (unsigned)c - row * (unsigned)lp.nx;
                unsigned cx = (unsigned)(lp.ixlo + (int)col);
                unsigned cy = (unsigned)(lp.iylo + (int)row);
                unsigned h  = cx ^ (cy * 2654435761u);
                regs[r]  = tbl[h & 65535u];
            }
        }
    };

    auto land = [&](const LP& lp, v2f* regs) {
        v2f* cb = arena + lp.off;
        #pragma unroll
        for (int r = 0; r < 3; ++r) {
            int c = tid + (r << 8);
            if (c < lp.ncorn) cb[c] = regs[r];
        }
    };

    const int ty = tid >> 4;     // 0..15 -> output rows 2ty, 2ty+1
    const int tx = tid & 15;
    const float* W = ws + 32 + b*864;    // Wp[l][tap][o][2]; l stride 54
    v2f accP0[3], accP1[3];
    #pragma unroll
    for (int o = 0; o < 3; ++o) { accP0[o] = (v2f){0.f, 0.f}; accP1[o] = (v2f){0.f, 0.f}; }

    // incremental halo coords: step 256 = 14*18 + 4
    const int hy_base = tid / HALO_X;
    const int hx_base = tid - hy_base*HALO_X;

    // bilinear: in-register separable coords. buf parity indexed by loop
    // counter i (not level) so it alternates under rotation.
    auto bilinear_phase = [&](int buf, const LP& lp) {
        const v2f* cbuf = arena + lp.off;
        v2f* fout = feat2[buf];
        const float base_x = ((float)gx0 + 0.5f) * lp.r512;
        const float base_y = ((float)gy0 + 0.5f) * lp.r512;
        int hy = hy_base, hx = hx_base, p = tid;
        #pragma unroll
        for (int it = 0; it < 3; ++it) {
            if (p < NPIX) {
                int gy = gy0 + hy, gx = gx0 + hx;
                v2f f = (v2f){0.f, 0.f};
                if ((unsigned)gx < 512u && (unsigned)gy < 512u) {
                    float px  = fmaf((float)hx, lp.r512, base_x);
                    float py  = fmaf((float)hy, lp.r512, base_y);
                    float pxf = floorf(px), pyf = floorf(py);
                    float fx  = px - pxf,   fy  = py - pyf;
                    int   sx  = (int)pxf - lp.ixlo;
                    int   sy  = (int)pyf - lp.iylo;
                    int   s00 = sy*lp.nx + sx;
                    v2f c00 = cbuf[s00],         c10 = cbuf[s00 + 1];
                    v2f c01 = cbuf[s00 + lp.nx], c11 = cbuf[s00 + lp.nx + 1];
                    v2f fxv = (v2f){fx, fx};
                    v2f fyv = (v2f){fy, fy};
                    v2f r0 = __builtin_elementwise_fma(fxv, c10 - c00, c00);
                    v2f r1 = __builtin_elementwise_fma(fxv, c11 - c01, c01);
                    f      = __builtin_elementwise_fma(fyv, r1 - r0, r0);
                }
                fout[p] = f;
            }
            hy += 14; hx += 4; p += 256;
            if (hx >= HALO_X) { hx -= HALO_X; hy += 1; }
        }
    };

    // conflict-free conv reads: v2f at dword (2ty+r)*36 + 2tx ->
    // bank = (8ty + 4r + 2tx) mod 32: 2 lanes/bank (free, m136).
    auto conv_phase = [&](int buf, int l) {
        const v2f* fb = feat2[buf] + (ty*2)*HALO_X + tx;
        v2f v[4][3];
        #pragma unroll
        for (int r = 0; r < 4; ++r) {
            v[r][0] = fb[r*HALO_X + 0];
            v[r][1] = fb[r*HALO_X + 1];
            v[r][2] = fb[r*HALO_X + 2];
        }
        const float* Wl = W + l*54;   // [tap][o][2]
        #pragma unroll
        for (int ky = 0; ky < 3; ++ky) {
            #pragma unroll
            for (int kx = 0; kx < 3; ++kx) {
                const float* Wt = Wl + (ky*3 + kx)*6;
                v2f f0 = v[ky][kx];       // output row 2ty
                v2f f1 = v[ky + 1][kx];   // output row 2ty+1
                #pragma unroll
                for (int o = 0; o < 3; ++o) {
                    v2f wp = *(const v2f*)(Wt + o*2);
                    accP0[o] = __builtin_elementwise_fma(wp, f0, accP0[o]);
                    accP1[o] = __builtin_elementwise_fma(wp, f1, accP1[o]);
                }
            }
        }
    };

    // ---- prologue: first level (rotated) ----
    v2f regs[3];
    int lC = phase;
    LP lpC = readLP(lC);
    issue_fetch(lC, lpC, regs);
    land(lpC, regs);
    __syncthreads();

    // ---- main loop: 1-deep prefetch, rotated level order ----
    for (int i = 0; i < NLVL; ++i) {
        if (i + 1 < NLVL) {
            int lN = (lC + 1) & 15;
            LP lpN = readLP(lN);
            issue_fetch(lN, lpN, regs);      // loads fly during bilinear
            bilinear_phase(i & 1, lpC);
            land(lpN, regs);                 // vmcnt drains here
            __syncthreads();
            conv_phase(i & 1, lC);
            lC = lN; lpC = lpN;
        } else {
            bilinear_phase(i & 1, lpC);
            __syncthreads();
            conv_phase(i & 1, lC);
        }
    }

    // ---- store: 2 row-adjacent px x 3 channels ----
    float acc[6];
    #pragma unroll
    for (int o = 0; o < 3; ++o) {
        acc[o]     = accP0[o].x + accP0[o].y + bias[o];
        acc[3 + o] = accP1[o].x + accP1[o].y + bias[o];
    }
    #pragma unroll
    for (int i = 0; i < 6; ++i)
        acc[i] = fminf(fmaxf(acc[i], -256.f), 256.f);

    const int gx = tileX*TILE_X + tx;
    const int gy = tileY*TILE_Y + ty*2;
    const int base0 = (gy << 9) + gx;
    const int base1 = base0 + 512;
    const int ob = (b*3) << 18;
    out[ob           + base0] = acc[0];
    out[ob + (1<<18) + base0] = acc[1];
    out[ob + (2<<18) + base0] = acc[2];
    out[ob           + base1] = acc[3];
    out[ob + (1<<18) + base1] = acc[4];
    out[ob + (2<<18) + base1] = acc[5];
}

extern "C" void kernel_launch(void* const* d_in, const int* in_sizes, int n_in,
                              void* d_out, int out_size, void* d_ws, size_t ws_size,
                              hipStream_t stream) {
    const float* x        = (const float*)d_in[0];
    const float* s        = (const float*)d_in[1];
    const float* weight   = (const float*)d_in[2];
    const float* affine_w = (const float*)d_in[3];
    const float* affine_b = (const float*)d_in[4];
    const float* bias     = (const float*)d_in[5];
    float* outp = (float*)d_out;
    float* wsf  = (float*)d_ws;

    prep_kernel<<<4, 256, 0, stream>>>(s, weight, affine_w, affine_b, wsf);
    main_kernel<<<2048, 256, 0, stream>>>(x, wsf, bias, outp);
}

// Round 17
// 50.712 us; speedup vs baseline: 1.0048x; 1.0048x over previous
//
#include <hip/hip_runtime.h>
#include <hip/hip_bf16.h>
#include <math.h>

#define TILE_X 16
#define TILE_Y 32
#define HALO_X 18
#define HALO_Y 34
#define NPIX   (HALO_X*HALO_Y)   // 612
#define NLVL   16
#define ARENA  1129              // max live pair: s(14)+s(15) = 464+665

typedef float v2f __attribute__((ext_vector_type(2)));

// Per-level corner arena offsets. Live set at iter l = {read l, write l+1};
// all such adjacent pairs disjoint; other overlaps barrier-separated in time.
// sizes: l0..l15 = 12,12,12,20,20,24,35,40,54,77,104,144,209,299,464,665
__device__ __constant__ const short LVL_OFF[16] =
    {1050,1038,1026,1006,986,962,927,887,833,756,652,508,299,0,665,0};

// ---------------- prep kernel: 4 blocks, one per batch ----------------
// ws layout (floats): [32..32+3456) Wp[b][l][tap][o][2]
__global__ __launch_bounds__(256) void prep_kernel(
    const float* __restrict__ s,        // (4,512)
    const float* __restrict__ weight,   // (3,32,3,3) = 864
    const float* __restrict__ affine_w, // (32,512)
    const float* __restrict__ affine_b, // (32,)
    float* __restrict__ ws)
{
    __shared__ float styles[32];
    __shared__ float dcoef[3];
    const int b   = blockIdx.x;
    const int tid = threadIdx.x;

    // styles[c] = dot(s[b,:], affine_w[c,:]) / sqrt(512) + affine_b[c]
    // 32 channels x 8 lanes = 256 threads exactly
    {
        int c = tid >> 3, g = tid & 7;
        const float4* sv = (const float4*)(s + b*512 + g*64);
        const float4* wv = (const float4*)(affine_w + c*512 + g*64);
        float acc = 0.f;
        #pragma unroll
        for (int k = 0; k < 16; ++k) {
            float4 a = sv[k], w = wv[k];
            acc += a.x*w.x + a.y*w.y + a.z*w.z + a.w*w.w;
        }
        acc += __shfl_xor(acc, 1);
        acc += __shfl_xor(acc, 2);
        acc += __shfl_xor(acc, 4);
        if (g == 0)
            styles[c] = acc * 0.044194173824159216f + affine_b[c];
    }
    __syncthreads();

    // dcoef[o] = rsqrt(sum_{c,k} (weight[o,c,k]*styles[c])^2 + 1e-8)
    if (tid < 24) {
        int o = tid >> 3, g = tid & 7;
        float sum = 0.f;
        #pragma unroll
        for (int ci = 0; ci < 4; ++ci) {
            int c = 4*g + ci;
            float st = styles[c];
            #pragma unroll
            for (int k = 0; k < 9; ++k) {
                float w = weight[o*288 + c*9 + k] * st;
                sum = fmaf(w, w, sum);
            }
        }
        sum += __shfl_xor(sum, 1);
        sum += __shfl_xor(sum, 2);
        sum += __shfl_xor(sum, 4);
        if (g == 0)
            dcoef[o] = 1.0f / sqrtf(sum + 1e-8f);
    }
    __syncthreads();

    // Wp[b][l][tap][o][p] = weight[o, 2l+p, tap] * styles[2l+p] * dcoef[o]
    for (int t = tid; t < 864; t += 256) {
        int l   = t / 54;  int r2 = t % 54;
        int tap = r2 / 6;  int r3 = r2 % 6;
        int o   = r3 >> 1; int p  = r3 & 1;
        int c   = 2*l + p;
        ws[32 + b*864 + t] = weight[o*288 + c*9 + tap] * styles[c] * dcoef[o];
    }
}

// ---------------- main fused kernel (R11/R15 structure — best known) -------
struct LP { int ixlo, iylo, nx, ncorn; unsigned magic; float r512; int off; };

__global__ __launch_bounds__(256, 8) void main_kernel(
    const float* __restrict__ tables,  // (4,16,65536,2)
    const float* __restrict__ ws,
    const float* __restrict__ bias,    // (3,)
    float* __restrict__ out)           // (4,3,512,512)
{
    __shared__ alignas(16) v2f feat2[2][NPIX];     // 9792 B
    __shared__ alignas(16) int lpbuf[NLVL][8];     // 512 B
    __shared__ v2f arena[ARENA];                   // 9032 B (per-level offsets)
    // total 19336 B -> 8 blocks/CU

    // XCD-aware bijective swizzle (2048 = 8 XCDs x 256): per-XCD gather
    // working set ~ one batch's fine tables -> fits private 4 MB L2.
    // (R7: FETCH 28.8 -> 8.1 MB.)
    const int blk   = ((blockIdx.x & 7) << 8) | (blockIdx.x >> 3);
    const int b     = blk >> 9;
    const int trem  = blk & 511;
    const int tileY = trem >> 5;        // 0..15
    const int tileX = trem & 31;        // 0..31
    const int gx0 = tileX*TILE_X - 1, gy0 = tileY*TILE_Y - 1;
    const int tid = threadIdx.x;

    const v2f* tbl_base = (const v2f*)tables;

    // ---- per-block LP table: 16 lanes compute all levels once ----
    if (tid < NLVL) {
        // res(l) = 16 * 2^(l/3) (growth = exp(ln32/15) = 2^(1/3) exactly)
        float res  = 16.0f * exp2f((float)tid * (1.0f/3.0f));
        float r512 = res * (1.0f/512.0f);
        int vx_lo = max(gx0, 0), vx_hi = min(gx0 + HALO_X - 1, 511);
        int vy_lo = max(gy0, 0), vy_hi = min(gy0 + HALO_Y - 1, 511);
        int xlo = (int)floorf((vx_lo + 0.5f) * r512);
        int xhi = (int)floorf((vx_hi + 0.5f) * r512);
        int ylo = (int)floorf((vy_lo + 0.5f) * r512);
        int yhi = (int)floorf((vy_hi + 0.5f) * r512);
        int nx = xhi - xlo + 2, ny = yhi - ylo + 2;
        lpbuf[tid][0] = xlo;
        lpbuf[tid][1] = ylo;
        lpbuf[tid][2] = nx;
        lpbuf[tid][3] = nx * ny;
        lpbuf[tid][4] = (int)(65536u / (unsigned)nx + 1u);
        lpbuf[tid][5] = __float_as_int(r512);
        lpbuf[tid][6] = (int)LVL_OFF[tid];
    }
    __syncthreads();

    auto readLP = [&](int l) {
        LP lp;
        int4 a = *(const int4*)&lpbuf[l][0];
        int4 c = *(const int4*)&lpbuf[l][4];
        lp.ixlo = a.x; lp.iylo = a.y; lp.nx = a.z; lp.ncorn = a.w;
        lp.magic = (unsigned)c.x; lp.r512 = __int_as_float(c.y); lp.off = c.z;
        return lp;
    };

    auto issue_fetch = [&](int lvl, const LP& lp, v2f* regs) {
        const v2f* tbl = tbl_base + ((size_t)((b << 4) + lvl) << 16);
        #pragma unroll
        for (int r = 0; r < 3; ++r) {
            int c = tid + (r << 8);
            if (c < lp.ncorn) {
                unsigned row = ((unsigned)c * lp.magic) >> 16;
                unsigned col = (unsigned)c - row * (unsigned)lp.nx;
                unsigned cx = (unsigned)(lp.ixlo + (int)col);
                unsigned cy = (unsigned)(lp.iylo + (int)row);
                unsigned h  = cx ^ (cy * 2654435761u);
                regs[r]  = tbl[h & 65535u];
            }
        }
    };

    auto land = [&](const LP& lp, v2f* regs) {
        v2f* cb = arena + lp.off;
        #pragma unroll
        for (int r = 0; r < 3; ++r) {
            int c = tid + (r << 8);
            if (c < lp.ncorn) cb[c] = regs[r];
        }
    };

    const int ty = tid >> 4;     // 0..15 -> output rows 2ty, 2ty+1
    const int tx = tid & 15;
    const float* W = ws + 32 + b*864;    // Wp[l][tap][o][2]; l stride 54
    v2f accP0[3], accP1[3];
    #pragma unroll
    for (int o = 0; o < 3; ++o) { accP0[o] = (v2f){0.f, 0.f}; accP1[o] = (v2f){0.f, 0.f}; }

    // incremental halo coords: step 256 = 14*18 + 4
    const int hy_base = tid / HALO_X;
    const int hx_base = tid - hy_base*HALO_X;

    // bilinear: in-register separable coords (no LDS tables; LDS pipe is
    // the binding resource — VALU has 4x the aggregate issue width)
    auto bilinear_phase = [&](int l, const LP& lp) {
        const v2f* cbuf = arena + lp.off;
        v2f* fout = feat2[l & 1];
        // px(hx) = (gx0+hx+0.5)*r512 = base_x + hx*r512
        const float base_x = ((float)gx0 + 0.5f) * lp.r512;
        const float base_y = ((float)gy0 + 0.5f) * lp.r512;
        int hy = hy_base, hx = hx_base, p = tid;
        #pragma unroll
        for (int it = 0; it < 3; ++it) {
            if (p < NPIX) {
                int gy = gy0 + hy, gx = gx0 + hx;
                v2f f = (v2f){0.f, 0.f};
                if ((unsigned)gx < 512u && (unsigned)gy < 512u) {
                    float px  = fmaf((float)hx, lp.r512, base_x);
                    float py  = fmaf((float)hy, lp.r512, base_y);
                    float pxf = floorf(px), pyf = floorf(py);
                    float fx  = px - pxf,   fy  = py - pyf;
                    int   sx  = (int)pxf - lp.ixlo;
                    int   sy  = (int)pyf - lp.iylo;
                    int   s00 = sy*lp.nx + sx;
                    v2f c00 = cbuf[s00],         c10 = cbuf[s00 + 1];
                    v2f c01 = cbuf[s00 + lp.nx], c11 = cbuf[s00 + lp.nx + 1];
                    v2f fxv = (v2f){fx, fx};
                    v2f fyv = (v2f){fy, fy};
                    v2f r0 = __builtin_elementwise_fma(fxv, c10 - c00, c00);
                    v2f r1 = __builtin_elementwise_fma(fxv, c11 - c01, c01);
                    f      = __builtin_elementwise_fma(fyv, r1 - r0, r0);
                }
                fout[p] = f;
            }
            hy += 14; hx += 4; p += 256;
            if (hx >= HALO_X) { hx -= HALO_X; hy += 1; }
        }
    };

    // conflict-free conv reads: v2f at dword (2ty+r)*36 + 2tx ->
    // bank = (8ty + 4r + 2tx) mod 32: 2 lanes/bank (free, m136).
    auto conv_phase = [&](int l) {
        const v2f* fb = feat2[l & 1] + (ty*2)*HALO_X + tx;
        v2f v[4][3];
        #pragma unroll
        for (int r = 0; r < 4; ++r) {
            v[r][0] = fb[r*HALO_X + 0];
            v[r][1] = fb[r*HALO_X + 1];
            v[r][2] = fb[r*HALO_X + 2];
        }
        const float* Wl = W + l*54;   // [tap][o][2]
        #pragma unroll
        for (int ky = 0; ky < 3; ++ky) {
            #pragma unroll
            for (int kx = 0; kx < 3; ++kx) {
                const float* Wt = Wl + (ky*3 + kx)*6;
                v2f f0 = v[ky][kx];       // output row 2ty
                v2f f1 = v[ky + 1][kx];   // output row 2ty+1
                #pragma unroll
                for (int o = 0; o < 3; ++o) {
                    v2f wp = *(const v2f*)(Wt + o*2);
                    accP0[o] = __builtin_elementwise_fma(wp, f0, accP0[o]);
                    accP1[o] = __builtin_elementwise_fma(wp, f1, accP1[o]);
                }
            }
        }
    };

    // ---- prologue: level 0 corners ----
    v2f regs[3];
    LP lpC = readLP(0);
    issue_fetch(0, lpC, regs);
    land(lpC, regs);
    __syncthreads();

    // ---- main loop: 1-deep prefetch (gathers are L2-hits post-swizzle) ----
    for (int l = 0; l < NLVL; ++l) {
        if (l + 1 < NLVL) {
            LP lpN = readLP(l + 1);
            issue_fetch(l + 1, lpN, regs);   // loads fly during bilinear
            bilinear_phase(l, lpC);
            land(lpN, regs);                 // vmcnt drains here
            __syncthreads();
            conv_phase(l);
            lpC = lpN;
        } else {
            bilinear_phase(l, lpC);
            __syncthreads();
            conv_phase(l);
        }
    }

    // ---- store: 2 row-adjacent px x 3 channels ----
    float acc[6];
    #pragma unroll
    for (int o = 0; o < 3; ++o) {
        acc[o]     = accP0[o].x + accP0[o].y + bias[o];
        acc[3 + o] = accP1[o].x + accP1[o].y + bias[o];
    }
    #pragma unroll
    for (int i = 0; i < 6; ++i)
        acc[i] = fminf(fmaxf(acc[i], -256.f), 256.f);

    const int gx = tileX*TILE_X + tx;
    const int gy = tileY*TILE_Y + ty*2;
    const int base0 = (gy << 9) + gx;
    const int base1 = base0 + 512;
    const int ob = (b*3) << 18;
    out[ob           + base0] = acc[0];
    out[ob + (1<<18) + base0] = acc[1];
    out[ob + (2<<18) + base0] = acc[2];
    out[ob           + base1] = acc[3];
    out[ob + (1<<18) + base1] = acc[4];
    out[ob + (2<<18) + base1] = acc[5];
}

extern "C" void kernel_launch(void* const* d_in, const int* in_sizes, int n_in,
                              void* d_out, int out_size, void* d_ws, size_t ws_size,
                              hipStream_t stream) {
    const float* x        = (const float*)d_in[0];
    const float* s        = (const float*)d_in[1];
    const float* weight   = (const float*)d_in[2];
    const float* affine_w = (const float*)d_in[3];
    const float* affine_b = (const float*)d_in[4];
    const float* bias     = (const float*)d_in[5];
    float* outp = (float*)d_out;
    float* wsf  = (float*)d_ws;

    prep_kernel<<<4, 256, 0, stream>>>(s, weight, affine_w, affine_b, wsf);
    main_kernel<<<2048, 256, 0, stream>>>(x, wsf, bias, outp);
}